// Round 19
// baseline (470.388 us; speedup 1.0000x reference)
//
#include <hip/hip_runtime.h>
#include <hip/hip_bf16.h>
#include <math.h>

#define B_    4
#define CIN   128
#define NPTS  2048
#define DIM   256
#define PH    64
#define HIDN  1024
#define KNN_  16
#define BN    (B_*NPTS)      /* 8192  */
#define CC    (BN*KNN_)      /* 131072 */
#define EPS_  1e-5f

typedef __bf16 bf16;
typedef __bf16 bf16x8 __attribute__((ext_vector_type(8)));
typedef __bf16 bf16x4 __attribute__((ext_vector_type(4)));
typedef float  f32x4  __attribute__((ext_vector_type(4)));

// raw barrier: lgkmcnt-only wait (LDS deps) + s_barrier. Unlike
// __syncthreads() the compiler does NOT drain vmcnt(0), so in-flight
// global (aw1/aw2) loads survive across the barrier. Correct here because
// the only cross-wave deps in the MLP loop are t_lds ds ops (lgkmcnt).
#define RAW_BAR() asm volatile("s_waitcnt lgkmcnt(0)\n\ts_barrier" ::: "memory")

// front kernel block ranges (prep + transpose + fold)
#define PREP_CNT  2245              /* prep: 574528 elems / 256           */
#define TR_END    (PREP_CNT + 128)  /* transpose: 128 blocks              */
#define FRONT_END (TR_END + 192)    /* fold: 768 o / 4 per block          */

// knn+gemm kernel block ranges
#define KNN_END   2048              /* knn: 2048 blocks (longest first)   */
#define KG_END    (KNN_END + 1536)  /* qkv gemm: 128 x 12 flattened       */

// ---------------------------------------------------------------------------
// FRONT kernel: prep casts + transpose + qkv/ls weight-fold.
// ---------------------------------------------------------------------------
__global__ __launch_bounds__(256) void front_kernel(
    const float* __restrict__ x, bf16* __restrict__ xT,
    const float* __restrict__ ls_w, const float* __restrict__ ls_b,
    const float* __restrict__ qw, const float* __restrict__ kw,
    const float* __restrict__ vw,
    const float* __restrict__ qb, const float* __restrict__ kb,
    const float* __restrict__ vb,
    const float* __restrict__ pw2,  const float* __restrict__ aw1,
    const float* __restrict__ aw2,  const float* __restrict__ lw,
    const float* __restrict__ pb1,  const float* __restrict__ pg,
    const float* __restrict__ pbeta,const float* __restrict__ pmean,
    const float* __restrict__ pvar,
    const float* __restrict__ ab1,  const float* __restrict__ ag,
    const float* __restrict__ abeta,const float* __restrict__ amean,
    const float* __restrict__ avar,
    bf16* pw2b, bf16* aw1b, bf16* aw2b, bf16* lwb,
    float* pe_scale, float* pe_shift, float* at_scale, float* at_shift,
    bf16* wfold, float* bfold)
{
  __shared__ __align__(16) float tile[CIN][65];   // transpose only
  const int bid = blockIdx.x;
  const int tid = threadIdx.x;

  if (bid < PREP_CNT) {
    long e = (long)bid * 256 + tid;
    if (e < 16384)  { pw2b[e] = (bf16)pw2[e]; return; } e -= 16384;
    if (e < 262144) { aw1b[e] = (bf16)aw1[e]; return; } e -= 262144;
    if (e < 262144) { aw2b[e] = (bf16)aw2[e]; return; } e -= 262144;
    if (e < 32768)  { lwb[e]  = (bf16)lw[e];  return; } e -= 32768;
    if (e < 64) {
      float sc = pg[e] * rsqrtf(pvar[e] + EPS_);
      pe_scale[e] = sc;
      pe_shift[e] = sc * pb1[e] + pbeta[e] - pmean[e] * sc;
      return;
    } e -= 64;
    if (e < 1024) {
      float sc = ag[e] * rsqrtf(avar[e] + EPS_);
      at_scale[e] = sc;
      at_shift[e] = sc * ab1[e] + abeta[e] - amean[e] * sc;
    }
    return;
  }

  if (bid < TR_END) {
    // ---------------- transpose x -> xT ----------------
    const int tb = bid - PREP_CNT;
    const int b = tb >> 5;
    const int n0 = (tb & 31) * 64;
    const float* xb = x + (long)b * CIN * NPTS;
#pragma unroll
    for (int it = 0; it < 32; ++it) {
      int row = it * 4 + (tid >> 6);
      int n = tid & 63;
      tile[row][n] = xb[(long)row * NPTS + n0 + n];
    }
    __syncthreads();
#pragma unroll
    for (int it = 0; it < 4; ++it) {
      int c = it * 256 + tid;
      int n = c >> 4;
      int ch0 = (c & 15) * 8;
      bf16x8 v;
#pragma unroll
      for (int j = 0; j < 8; ++j) v[j] = (bf16)tile[ch0 + j][n];
      *(bf16x8*)&xT[((long)b * NPTS + n0 + n) * CIN + ch0] = v;
    }
    return;
  }

  {
    // ---------------- weight fold: one o per wave ----------------
    const int lane = tid & 63, wave = tid >> 6;
    const int o = (bid - TR_END) * 4 + wave;       // 0..767
    const float* wsrc; const float* bsrc; int oo;
    if (o < 256)      { wsrc = qw + (long)o * DIM;        bsrc = qb; oo = o; }
    else if (o < 512) { wsrc = kw + (long)(o - 256) * DIM; bsrc = kb; oo = o - 256; }
    else              { wsrc = vw + (long)(o - 512) * DIM; bsrc = vb; oo = o - 512; }
    const int c0 = lane, c1 = lane + 64;
    float acc0 = 0.f, acc1 = 0.f, accb = 0.f;
    for (int dd = 0; dd < DIM; ++dd) {
      float w = wsrc[dd];                          // uniform -> scalar load
      acc0 += w * ls_w[(long)dd * CIN + c0];
      acc1 += w * ls_w[(long)dd * CIN + c1];
      accb += w * ls_b[dd];
    }
    wfold[(long)o * CIN + c0] = (bf16)acc0;
    wfold[(long)o * CIN + c1] = (bf16)acc1;
    if (lane == 0) bfold[o] = accb + bsrc[oo];
  }
}

// ---------------------------------------------------------------------------
// KNN + QKV-GEMM kernel: block-range fusion (knn first, GEMM overlaps).
// ---------------------------------------------------------------------------
__global__ __launch_bounds__(256) void knn_gemm_kernel(
    const float* __restrict__ pos, int* __restrict__ idx_out,
    const bf16* __restrict__ inT, const bf16* __restrict__ Wb,
    const float* __restrict__ bias, bf16* __restrict__ outp)
{
  __shared__ float smem[3 * NPTS];    // knn branch only (24576 B)
  const int bid = blockIdx.x;
  const int tid = threadIdx.x;
  const int lane = tid & 63, wave = tid >> 6;

  if (bid < KNN_END) {
    // ---------------- KNN: wave-per-query ----------------
    float* px = smem;
    float* py = px + NPTS;
    float* pz = py + NPTS;
    const int q = bid * 4 + wave;
    const int b = q >> 11;
    const int n = q & (NPTS - 1);
    const float* p = pos + (long)b * 3 * NPTS;
    for (int j = tid; j < NPTS; j += 256) {
      px[j] = p[j]; py[j] = p[NPTS + j]; pz[j] = p[2 * NPTS + j];
    }
    __syncthreads();
    float qx = px[n], qy = py[n], qz = pz[n];
    float qs = qx * qx + qy * qy + qz * qz;
    float d[32];
#pragma unroll
    for (int j = 0; j < 32; ++j) {
      int pt = j * 64 + lane;
      float xx = px[pt], yy = py[pt], zz = pz[pt];
      float s2 = xx * xx + yy * yy + zz * zz;
      float dt = qx * xx + qy * yy + qz * zz;
      d[j] = qs + s2 - 2.f * dt;
    }
    for (int r = 0; r < KNN_; ++r) {
      float bv = 1e30f; int bj = 0;
#pragma unroll
      for (int j = 0; j < 32; ++j)
        if (d[j] < bv) { bv = d[j]; bj = j; }
      int bi = bj * 64 + lane;
#pragma unroll
      for (int off = 32; off >= 1; off >>= 1) {
        float ov = __shfl_xor(bv, off);
        int   oi = __shfl_xor(bi, off);
        if (ov < bv || (ov == bv && oi < bi)) { bv = ov; bi = oi; }
      }
      if (lane == 0) idx_out[(long)q * KNN_ + r] = bi;
#pragma unroll
      for (int j = 0; j < 32; ++j)
        if (bi == j * 64 + lane) d[j] = 1e30f;
    }
    return;
  }

  {
    // ---------------- qkv GEMM: 64x64 tile, KD=128, O=768 ----------------
    const int g = bid - KNN_END;           // 0..1535
    const int row16 = lane & 15, grp = lane >> 4;
    const long i0 = (long)(g & 127) * 64 + (wave & 1) * 32;
    const long o0 = (long)(g >> 7) * 64 + (wave >> 1) * 32;
    f32x4 acc[2][2] = {};
    const bf16* a0p = inT + (i0 + row16) * 128 + grp * 8;
    const bf16* a1p = a0p + 16 * 128;
    const bf16* b0p = Wb + (o0 + row16) * 128 + grp * 8;
    const bf16* b1p = b0p + 16 * 128;
#pragma unroll
    for (int ks = 0; ks < 4; ++ks) {
      bf16x8 a0 = *(const bf16x8*)(a0p + ks * 32);
      bf16x8 a1 = *(const bf16x8*)(a1p + ks * 32);
      bf16x8 b0 = *(const bf16x8*)(b0p + ks * 32);
      bf16x8 b1 = *(const bf16x8*)(b1p + ks * 32);
      acc[0][0] = __builtin_amdgcn_mfma_f32_16x16x32_bf16(a0, b0, acc[0][0], 0, 0, 0);
      acc[0][1] = __builtin_amdgcn_mfma_f32_16x16x32_bf16(a0, b1, acc[0][1], 0, 0, 0);
      acc[1][0] = __builtin_amdgcn_mfma_f32_16x16x32_bf16(a1, b0, acc[1][0], 0, 0, 0);
      acc[1][1] = __builtin_amdgcn_mfma_f32_16x16x32_bf16(a1, b1, acc[1][1], 0, 0, 0);
    }
#pragma unroll
    for (int ot = 0; ot < 2; ++ot) {
      long o = o0 + ot * 16 + row16;
      float bv = bias[o];
#pragma unroll
      for (int it = 0; it < 2; ++it) {
#pragma unroll
        for (int r = 0; r < 4; ++r) {
          long i = i0 + it * 16 + grp * 4 + r;
          outp[i * 768 + o] = (bf16)(acc[it][ot][r] + bv);
        }
      }
    }
  }
}

// ---------------------------------------------------------------------------
// FUSED attention kernel, v18b: R13/R17 config + ONE delta: the 16 in-loop
// barriers use RAW_BAR (lgkmcnt-only) instead of __syncthreads (which
// drains vmcnt(0), forcing the next chunk's aw1/aw2 L2 prefetches to
// retire before the barrier). Zero register cost — sidesteps the spill
// wall that killed every register-based pipelining attempt (R3-R5, R11).
// ---------------------------------------------------------------------------
__global__ __launch_bounds__(512, 4) void attn_fused_kernel(
    const bf16* __restrict__ qkvT, const float* __restrict__ pos,
    const int* __restrict__ idx, const float* __restrict__ pw1,
    const float* __restrict__ pe_scale, const float* __restrict__ pe_shift,
    const bf16* __restrict__ pw2b, const float* __restrict__ pb2,
    const bf16* __restrict__ aw1b, const bf16* __restrict__ aw2b,
    const float* __restrict__ at_scale, const float* __restrict__ at_shift,
    const float* __restrict__ ab2, bf16* __restrict__ aggT)
{
  __shared__ __align__(16) bf16 u_lds[64 * 256];  // 32 KB, swizzled
  __shared__ __align__(16) bf16 tbuf[64 * 128];   // 16 KB: t / hid overlay
  __shared__ float rel_lds[64][4];
  __shared__ int   idx_lds[64];
  bf16* t_lds   = tbuf;                 // row stride 128, swizzled
  bf16* hid_lds = tbuf;                 // row stride 64, swizzled (8 KB)

  const int tid = threadIdx.x;
  const int lane = tid & 63, wave = tid >> 6;     // wave in [0,8)
  const int row16 = lane & 15, grp = lane >> 4;
  const int r7 = row16 & 7;
  const long c0 = (long)blockIdx.x * 64;
  const int bn0 = blockIdx.x * 4;
  const int b = bn0 >> 11;
  const float* pB = pos + (long)b * 3 * NPTS;
  const int os = wave * 32;             // this wave's 32-wide output slab

  // ---- stage idx + pos_rel + k rows (swizzled u write) ----
  if (tid < 64) {
    int nb = idx[c0 + tid];
    idx_lds[tid] = nb;
    int n = (bn0 + (tid >> 4)) & (NPTS - 1);
    rel_lds[tid][0] = pB[n] - pB[nb];
    rel_lds[tid][1] = pB[NPTS + n] - pB[NPTS + nb];
    rel_lds[tid][2] = pB[2 * NPTS + n] - pB[2 * NPTS + nb];
  }
#pragma unroll
  for (int it = 0; it < 4; ++it) {
    int id = it * 512 + tid;
    int col = id >> 5, ch16 = id & 31;
    int nb = idx[c0 + col];
    *(bf16x8*)&u_lds[col * 256 + ((ch16 ^ (col & 7)) << 3)] =
        *(const bf16x8*)(qkvT + ((long)b * NPTS + nb) * 768 + 256 + ch16 * 8);
  }
  __syncthreads();

  // ---- hid = relu(bn(pw1 . rel)) -> one swizzled b128 store/thread ----
  {
    int c = tid & 63, jq = tid >> 6;   // jq in [0,8)
    float rx = rel_lds[c][0], ry = rel_lds[c][1], rz = rel_lds[c][2];
    bf16x8 pk8;
#pragma unroll
    for (int jj = 0; jj < 8; ++jj) {
      int j = jq * 8 + jj;
      float v = pw1[j * 3] * rx + pw1[j * 3 + 1] * ry + pw1[j * 3 + 2] * rz;
      v = pe_scale[j] * v + pe_shift[j];
      pk8[jj] = (bf16)fmaxf(v, 0.f);
    }
    *(bf16x8*)&hid_lds[c * 64 + ((jq ^ (c & 7)) << 3)] = pk8;
  }
  __syncthreads();

  // ---- pe GEMM: accpe[ct][ot] holds pe[c=ct*16+grp*4+r][o=os+ot*16+row16] ----
  f32x4 accpe[4][2] = {};
#pragma unroll
  for (int ks = 0; ks < 2; ++ks) {
    bf16x8 ah[4];
#pragma unroll
    for (int ct = 0; ct < 4; ++ct)
      ah[ct] = *(const bf16x8*)&hid_lds[(ct * 16 + row16) * 64 + (((ks * 4 + grp) ^ r7) << 3)];
#pragma unroll
    for (int ot = 0; ot < 2; ++ot) {
      bf16x8 bw = *(const bf16x8*)(pw2b + (long)(os + ot * 16 + row16) * PH + ks * 32 + grp * 8);
#pragma unroll
      for (int ct = 0; ct < 4; ++ct)
        accpe[ct][ot] = __builtin_amdgcn_mfma_f32_16x16x32_bf16(ah[ct], bw, accpe[ct][ot], 0, 0, 0);
    }
  }

  // ---- u = q - k + pe (RMW on this wave's o-slab); keep pe as bf16 ----
  bf16x4 pe_bf[4][2];
#pragma unroll
  for (int ot = 0; ot < 2; ++ot) {
    int o = os + ot * 16 + row16;
    float pb2v = pb2[o];
#pragma unroll
    for (int ct = 0; ct < 4; ++ct) {
      float qv = (float)qkvT[(long)(bn0 + ct) * 768 + o];
#pragma unroll
      for (int r = 0; r < 4; ++r) {
        int c = ct * 16 + grp * 4 + r;
        int ua = c * 256 + (((o >> 3) ^ (c & 7)) << 3) + (o & 7);
        float pev = accpe[ct][ot][r] + pb2v;
        float kv = (float)u_lds[ua];
        u_lds[ua] = (bf16)(qv - kv + pev);
        pe_bf[ct][ot][r] = (bf16)pev;
      }
    }
  }
  __syncthreads();

  // ---- MLP: attn = ab2 + aw2 . relu(bn(aw1 . u)), HID chunked at 128 ----
  const int hs16 = wave * 16;
  f32x4 acc2[4][2] = {};
  for (int jc = 0; jc < 8; ++jc) {
    const int hg = jc * 128 + hs16;
    // GEMM1 (A=aw1 rows=j, B=u cols=c): D row=j, col=c
    f32x4 acc1[4] = {};
#pragma unroll
    for (int ks = 0; ks < 8; ++ks) {
      bf16x8 bu[4];
      const int ublk = ((ks * 4 + grp) ^ r7) << 3;
#pragma unroll
      for (int ct = 0; ct < 4; ++ct)
        bu[ct] = *(const bf16x8*)&u_lds[(ct * 16 + row16) * 256 + ublk];
      bf16x8 aw = *(const bf16x8*)(aw1b + (long)(hg + row16) * DIM + ks * 32 + grp * 8);
#pragma unroll
      for (int ct = 0; ct < 4; ++ct)
        acc1[ct] = __builtin_amdgcn_mfma_f32_16x16x32_bf16(aw, bu[ct], acc1[ct], 0, 0, 0);
    }
    // epilogue: lane holds t[c=ct*16+row16][j=hg+grp*4+r] -> swizzled b64
    {
      f32x4 sc4 = *(const f32x4*)&at_scale[hg + grp * 4];
      f32x4 sh4 = *(const f32x4*)&at_shift[hg + grp * 4];
#pragma unroll
      for (int ct = 0; ct < 4; ++ct) {
        bf16x4 pk;
#pragma unroll
        for (int r = 0; r < 4; ++r) {
          float v = sc4[r] * acc1[ct][r] + sh4[r];
          pk[r] = (bf16)fmaxf(v, 0.f);
        }
        int trow = ct * 16 + row16;
        int tblk = (wave * 2 + (grp >> 1)) ^ (trow & 7);
        *(bf16x4*)&t_lds[trow * 128 + (tblk << 3) + ((grp & 1) << 2)] = pk;
      }
    }
    RAW_BAR();                          // lgkmcnt-only: aw loads stay in flight
    // GEMM2: acc2[c][o] += t[c][j] * aw2[o][j]
#pragma unroll
    for (int ks2 = 0; ks2 < 4; ++ks2) {
      bf16x8 a2[4], b2;
#pragma unroll
      for (int ct = 0; ct < 4; ++ct)
        a2[ct] = *(const bf16x8*)&t_lds[(ct * 16 + row16) * 128 + (((ks2 * 4 + grp) ^ r7) << 3)];
#pragma unroll
      for (int ot = 0; ot < 2; ++ot) {
        b2 = *(const bf16x8*)(aw2b + (long)(os + ot * 16 + row16) * HIDN + jc * 128 + ks2 * 32 + grp * 8);
#pragma unroll
        for (int ct = 0; ct < 4; ++ct)
          acc2[ct][ot] = __builtin_amdgcn_mfma_f32_16x16x32_bf16(a2[ct], b2, acc2[ct][ot], 0, 0, 0);
      }
    }
    RAW_BAR();                          // lgkmcnt-only
  }

  // ---- softmax over K (k = grp*4+r across grp-lanes) + aggregation ----
#pragma unroll
  for (int ct = 0; ct < 4; ++ct) {
#pragma unroll
    for (int ot = 0; ot < 2; ++ot) {
      int o = os + ot * 16 + row16;
      float ab = ab2[o];
      float l[4];
      float m = -1e30f;
#pragma unroll
      for (int r = 0; r < 4; ++r) {
        l[r] = acc2[ct][ot][r] + ab;
        m = fmaxf(m, l[r]);
      }
      m = fmaxf(m, __shfl_xor(m, 16));
      m = fmaxf(m, __shfl_xor(m, 32));
      float s = 0.f;
#pragma unroll
      for (int r = 0; r < 4; ++r) { l[r] = __expf(l[r] - m); s += l[r]; }
      s += __shfl_xor(s, 16);
      s += __shfl_xor(s, 32);
      float inv = 1.f / s;
      float agg = 0.f;
#pragma unroll
      for (int r = 0; r < 4; ++r) {
        int c = ct * 16 + grp * 4 + r;
        int nb = idx_lds[c];
        float vv = (float)qkvT[((long)b * NPTS + nb) * 768 + 512 + o];
        agg += l[r] * (vv + (float)pe_bf[ct][ot][r]);
      }
      agg *= inv;
      agg += __shfl_xor(agg, 16);
      agg += __shfl_xor(agg, 32);
      if (grp == 0) aggT[(long)(bn0 + ct) * DIM + o] = (bf16)agg;
    }
  }
}

// ---------------------------------------------------------------------------
// final: out[b][o][n] = lw . agg + lb + identity  (fp32, channel-major out)
// ---------------------------------------------------------------------------
__global__ __launch_bounds__(256) void final_kernel(
    const bf16* __restrict__ aggT, const bf16* __restrict__ lwb,
    const float* __restrict__ lb, const float* __restrict__ x,
    float* __restrict__ out)
{
  const int tid = threadIdx.x;
  const int lane = tid & 63, wave = tid >> 6;
  const int row16 = lane & 15, grp = lane >> 4;
  const long i0 = (long)blockIdx.x * 64 + (wave & 1) * 32;
  const int o0 = blockIdx.y * 64 + (wave >> 1) * 32;
  f32x4 acc[2][2] = {};
  const bf16* a0p = aggT + (i0 + row16) * DIM + grp * 8;
  const bf16* a1p = a0p + 16 * DIM;
  const bf16* b0p = lwb + (long)(o0 + row16) * DIM + grp * 8;
  const bf16* b1p = b0p + 16 * DIM;
#pragma unroll
  for (int ks = 0; ks < 8; ++ks) {
    bf16x8 a0 = *(const bf16x8*)(a0p + ks * 32);
    bf16x8 a1 = *(const bf16x8*)(a1p + ks * 32);
    bf16x8 b0 = *(const bf16x8*)(b0p + ks * 32);
    bf16x8 b1 = *(const bf16x8*)(b1p + ks * 32);
    acc[0][0] = __builtin_amdgcn_mfma_f32_16x16x32_bf16(a0, b0, acc[0][0], 0, 0, 0);
    acc[0][1] = __builtin_amdgcn_mfma_f32_16x16x32_bf16(a0, b1, acc[0][1], 0, 0, 0);
    acc[1][0] = __builtin_amdgcn_mfma_f32_16x16x32_bf16(a1, b0, acc[1][0], 0, 0, 0);
    acc[1][1] = __builtin_amdgcn_mfma_f32_16x16x32_bf16(a1, b1, acc[1][1], 0, 0, 0);
  }
#pragma unroll
  for (int ot = 0; ot < 2; ++ot) {
    int o = o0 + ot * 16 + row16;
    float bv = lb[o];
#pragma unroll
    for (int it = 0; it < 2; ++it) {
#pragma unroll
      for (int r = 0; r < 4; ++r) {
        long i = i0 + it * 16 + grp * 4 + r;
        int bb = (int)(i >> 11);
        int n = (int)(i & (NPTS - 1));
        long off = ((long)bb * CIN + o) * NPTS + n;
        out[off] = acc[it][ot][r] + bv + x[off];
      }
    }
  }
}

// ---------------------------------------------------------------------------
extern "C" void kernel_launch(void* const* d_in, const int* in_sizes, int n_in,
                              void* d_out, int out_size, void* d_ws, size_t ws_size,
                              hipStream_t stream)
{
  const float* x     = (const float*)d_in[0];
  const float* pos   = (const float*)d_in[1];
  const float* ls_w  = (const float*)d_in[2];
  const float* ls_b  = (const float*)d_in[3];
  const float* kw    = (const float*)d_in[4];
  const float* kb    = (const float*)d_in[5];
  const float* qw    = (const float*)d_in[6];
  const float* qb    = (const float*)d_in[7];
  const float* vw    = (const float*)d_in[8];
  const float* vb    = (const float*)d_in[9];
  const float* pw1   = (const float*)d_in[10];
  const float* pb1   = (const float*)d_in[11];
  const float* pg    = (const float*)d_in[12];
  const float* pbeta = (const float*)d_in[13];
  const float* pmean = (const float*)d_in[14];
  const float* pvar  = (const float*)d_in[15];
  const float* pw2   = (const float*)d_in[16];
  const float* pb2   = (const float*)d_in[17];
  const float* aw1   = (const float*)d_in[18];
  const float* ab1   = (const float*)d_in[19];
  const float* ag    = (const float*)d_in[20];
  const float* abeta = (const float*)d_in[21];
  const float* amean = (const float*)d_in[22];
  const float* avar  = (const float*)d_in[23];
  const float* aw2   = (const float*)d_in[24];
  const float* ab2   = (const float*)d_in[25];
  const float* lw    = (const float*)d_in[26];
  const float* lb    = (const float*)d_in[27];

  char* ws = (char*)d_ws;
  size_t off = 0;
  auto alloc = [&](size_t bytes) -> void* {
    void* p = ws + off;
    off = (off + bytes + 255) & ~(size_t)255;
    return p;
  };

  bf16* pw2b  = (bf16*)alloc(16384 * 2);
  bf16* aw1b  = (bf16*)alloc(262144 * 2);
  bf16* aw2b  = (bf16*)alloc(262144 * 2);
  bf16* lwb   = (bf16*)alloc(32768 * 2);
  float* pe_scale = (float*)alloc(64 * 4);
  float* pe_shift = (float*)alloc(64 * 4);
  float* at_scale = (float*)alloc(1024 * 4);
  float* at_shift = (float*)alloc(1024 * 4);
  bf16* wfold = (bf16*)alloc(98304 * 2);    // 768 x 128
  float* bfold = (float*)alloc(768 * 4);
  int*  idx  = (int*)alloc((size_t)CC * 4);
  bf16* xT   = (bf16*)alloc((size_t)BN * CIN * 2);
  bf16* qkvT = (bf16*)alloc((size_t)BN * 768 * 2);
  bf16* aggT = (bf16*)alloc((size_t)BN * DIM * 2);

  // 1. front: prep + transpose + weight-fold
  front_kernel<<<dim3(FRONT_END), 256, 0, stream>>>(
      x, xT, ls_w, ls_b, qw, kw, vw, qb, kb, vb,
      pw2, aw1, aw2, lw,
      pb1, pg, pbeta, pmean, pvar, ab1, ag, abeta, amean, avar,
      pw2b, aw1b, aw2b, lwb,
      pe_scale, pe_shift, at_scale, at_shift,
      wfold, bfold);

  // 2. knn + qkv GEMM fused (independent work, knn overlaps GEMM)
  knn_gemm_kernel<<<dim3(KG_END), 256, 0, stream>>>(
      pos, idx, xT, wfold, bfold, qkvT);

  // 3. fused attention (pe + u + MLP + softmax + agg) — 512 thr / 8 waves
  attn_fused_kernel<<<dim3(CC / 64), 512, 0, stream>>>(
      qkvT, pos, idx, pw1, pe_scale, pe_shift, pw2b, pb2,
      aw1b, aw2b, at_scale, at_shift, ab2, aggT);

  // 4. y = lw . agg + lb + identity
  final_kernel<<<dim3(BN / 64, CIN / 64), 256, 0, stream>>>(aggT, lwb, lb, x, (float*)d_out);
}

// Round 20
// 459.678 us; speedup vs baseline: 1.0233x; 1.0233x over previous
//
#include <hip/hip_runtime.h>
#include <hip/hip_bf16.h>
#include <math.h>

#define B_    4
#define CIN   128
#define NPTS  2048
#define DIM   256
#define PH    64
#define HIDN  1024
#define KNN_  16
#define BN    (B_*NPTS)      /* 8192  */
#define CC    (BN*KNN_)      /* 131072 */
#define EPS_  1e-5f

typedef __bf16 bf16;
typedef __bf16 bf16x8 __attribute__((ext_vector_type(8)));
typedef __bf16 bf16x4 __attribute__((ext_vector_type(4)));
typedef float  f32x4  __attribute__((ext_vector_type(4)));

// combo block ranges
#define KNN_END   2048              /* knn: 2048 blocks                   */
#define PREP_CNT  2245              /* prep: 574528 elems / 256           */
#define PREP_END  (KNN_END + PREP_CNT)
#define TR_END    (PREP_END + 128)  /* transpose: 128 blocks              */
#define FOLD_END  (TR_END + 192)    /* fold: 768 o / 4 per block          */

// ---------------------------------------------------------------------------
// COMBO front kernel: knn + prep + transpose + qkv/ls weight-fold in one
// launch (block-range dispatch).
// ---------------------------------------------------------------------------
__global__ __launch_bounds__(256) void combo_kernel(
    const float* __restrict__ pos, int* __restrict__ idx_out,
    const float* __restrict__ x, bf16* __restrict__ xT,
    const float* __restrict__ ls_w, const float* __restrict__ ls_b,
    const float* __restrict__ qw, const float* __restrict__ kw,
    const float* __restrict__ vw,
    const float* __restrict__ qb, const float* __restrict__ kb,
    const float* __restrict__ vb,
    const float* __restrict__ pw2,  const float* __restrict__ aw1,
    const float* __restrict__ aw2,  const float* __restrict__ lw,
    const float* __restrict__ pb1,  const float* __restrict__ pg,
    const float* __restrict__ pbeta,const float* __restrict__ pmean,
    const float* __restrict__ pvar,
    const float* __restrict__ ab1,  const float* __restrict__ ag,
    const float* __restrict__ abeta,const float* __restrict__ amean,
    const float* __restrict__ avar,
    bf16* pw2b, bf16* aw1b, bf16* aw2b, bf16* lwb,
    float* pe_scale, float* pe_shift, float* at_scale, float* at_shift,
    bf16* wfold, float* bfold)
{
  __shared__ __align__(16) char smem[33280];  // union: knn 24576 / tr 33280
  const int bid = blockIdx.x;
  const int tid = threadIdx.x;

  if (bid < KNN_END) {
    // ---------------- KNN: wave-per-query ----------------
    float* px = (float*)smem;
    float* py = px + NPTS;
    float* pz = py + NPTS;
    const int lane = tid & 63, wave = tid >> 6;
    const int q = bid * 4 + wave;
    const int b = q >> 11;
    const int n = q & (NPTS - 1);
    const float* p = pos + (long)b * 3 * NPTS;
    for (int j = tid; j < NPTS; j += 256) {
      px[j] = p[j]; py[j] = p[NPTS + j]; pz[j] = p[2 * NPTS + j];
    }
    __syncthreads();
    float qx = px[n], qy = py[n], qz = pz[n];
    float qs = qx * qx + qy * qy + qz * qz;
    float d[32];
#pragma unroll
    for (int j = 0; j < 32; ++j) {
      int pt = j * 64 + lane;
      float xx = px[pt], yy = py[pt], zz = pz[pt];
      float s2 = xx * xx + yy * yy + zz * zz;
      float dt = qx * xx + qy * yy + qz * zz;
      d[j] = qs + s2 - 2.f * dt;
    }
    for (int r = 0; r < KNN_; ++r) {
      float bv = 1e30f; int bj = 0;
#pragma unroll
      for (int j = 0; j < 32; ++j)
        if (d[j] < bv) { bv = d[j]; bj = j; }
      int bi = bj * 64 + lane;
#pragma unroll
      for (int off = 32; off >= 1; off >>= 1) {
        float ov = __shfl_xor(bv, off);
        int   oi = __shfl_xor(bi, off);
        if (ov < bv || (ov == bv && oi < bi)) { bv = ov; bi = oi; }
      }
      if (lane == 0) idx_out[(long)q * KNN_ + r] = bi;
#pragma unroll
      for (int j = 0; j < 32; ++j)
        if (bi == j * 64 + lane) d[j] = 1e30f;
    }
    return;
  }

  if (bid < PREP_END) {
    // ---------------- prep: casts + bn fold ----------------
    long e = (long)(bid - KNN_END) * 256 + tid;
    if (e < 16384)  { pw2b[e] = (bf16)pw2[e]; return; } e -= 16384;
    if (e < 262144) { aw1b[e] = (bf16)aw1[e]; return; } e -= 262144;
    if (e < 262144) { aw2b[e] = (bf16)aw2[e]; return; } e -= 262144;
    if (e < 32768)  { lwb[e]  = (bf16)lw[e];  return; } e -= 32768;
    if (e < 64) {
      float sc = pg[e] * rsqrtf(pvar[e] + EPS_);
      pe_scale[e] = sc;
      pe_shift[e] = sc * pb1[e] + pbeta[e] - pmean[e] * sc;
      return;
    } e -= 64;
    if (e < 1024) {
      float sc = ag[e] * rsqrtf(avar[e] + EPS_);
      at_scale[e] = sc;
      at_shift[e] = sc * ab1[e] + abeta[e] - amean[e] * sc;
    }
    return;
  }

  if (bid < TR_END) {
    // ---------------- transpose x -> xT ----------------
    float (*tile)[65] = (float(*)[65])smem;
    const int tb = bid - PREP_END;
    const int b = tb >> 5;
    const int n0 = (tb & 31) * 64;
    const float* xb = x + (long)b * CIN * NPTS;
#pragma unroll
    for (int it = 0; it < 32; ++it) {
      int row = it * 4 + (tid >> 6);
      int n = tid & 63;
      tile[row][n] = xb[(long)row * NPTS + n0 + n];
    }
    __syncthreads();
#pragma unroll
    for (int it = 0; it < 4; ++it) {
      int c = it * 256 + tid;
      int n = c >> 4;
      int ch0 = (c & 15) * 8;
      bf16x8 v;
#pragma unroll
      for (int j = 0; j < 8; ++j) v[j] = (bf16)tile[ch0 + j][n];
      *(bf16x8*)&xT[((long)b * NPTS + n0 + n) * CIN + ch0] = v;
    }
    return;
  }

  {
    // ---------------- weight fold: one o per wave ----------------
    const int lane = tid & 63, wave = tid >> 6;
    const int o = (bid - TR_END) * 4 + wave;       // 0..767
    const float* wsrc; const float* bsrc; int oo;
    if (o < 256)      { wsrc = qw + (long)o * DIM;        bsrc = qb; oo = o; }
    else if (o < 512) { wsrc = kw + (long)(o - 256) * DIM; bsrc = kb; oo = o - 256; }
    else              { wsrc = vw + (long)(o - 512) * DIM; bsrc = vb; oo = o - 512; }
    const int c0 = lane, c1 = lane + 64;
    float acc0 = 0.f, acc1 = 0.f, accb = 0.f;
    for (int dd = 0; dd < DIM; ++dd) {
      float w = wsrc[dd];                          // uniform -> scalar load
      acc0 += w * ls_w[(long)dd * CIN + c0];
      acc1 += w * ls_w[(long)dd * CIN + c1];
      accb += w * ls_b[dd];
    }
    wfold[(long)o * CIN + c0] = (bf16)acc0;
    wfold[(long)o * CIN + c1] = (bf16)acc1;
    if (lane == 0) bfold[o] = accb + bsrc[oo];
  }
}

// ---------------------------------------------------------------------------
// generic channel-last GEMM: out[i][o] = sum_k inT[i][k]*W[o][k] + bias[o]
// ---------------------------------------------------------------------------
template<int KD, bool OBF16>
__global__ __launch_bounds__(256) void gemmT_kernel(
    const bf16* __restrict__ inT, const bf16* __restrict__ Wb,
    const float* __restrict__ bias, void* __restrict__ outp, int O)
{
  const int tid = threadIdx.x;
  const int lane = tid & 63, wave = tid >> 6;
  const int row16 = lane & 15, grp = lane >> 4;
  const long i0 = (long)blockIdx.x * 64 + (wave & 1) * 32;
  const long o0 = (long)blockIdx.y * 64 + (wave >> 1) * 32;
  f32x4 acc[2][2] = {};
  const bf16* a0p = inT + (i0 + row16) * KD + grp * 8;
  const bf16* a1p = a0p + 16 * KD;
  const bf16* b0p = Wb + (o0 + row16) * KD + grp * 8;
  const bf16* b1p = b0p + 16 * KD;
#pragma unroll
  for (int ks = 0; ks < KD / 32; ++ks) {
    bf16x8 a0 = *(const bf16x8*)(a0p + ks * 32);
    bf16x8 a1 = *(const bf16x8*)(a1p + ks * 32);
    bf16x8 b0 = *(const bf16x8*)(b0p + ks * 32);
    bf16x8 b1 = *(const bf16x8*)(b1p + ks * 32);
    acc[0][0] = __builtin_amdgcn_mfma_f32_16x16x32_bf16(a0, b0, acc[0][0], 0, 0, 0);
    acc[0][1] = __builtin_amdgcn_mfma_f32_16x16x32_bf16(a0, b1, acc[0][1], 0, 0, 0);
    acc[1][0] = __builtin_amdgcn_mfma_f32_16x16x32_bf16(a1, b0, acc[1][0], 0, 0, 0);
    acc[1][1] = __builtin_amdgcn_mfma_f32_16x16x32_bf16(a1, b1, acc[1][1], 0, 0, 0);
  }
#pragma unroll
  for (int ot = 0; ot < 2; ++ot) {
    long o = o0 + ot * 16 + row16;
    float bv = bias[o];
#pragma unroll
    for (int it = 0; it < 2; ++it) {
#pragma unroll
      for (int r = 0; r < 4; ++r) {
        long i = i0 + it * 16 + grp * 4 + r;
        float v = acc[it][ot][r] + bv;
        if (OBF16) ((bf16*)outp)[i * O + o] = (bf16)v;
        else       ((float*)outp)[i * O + o] = v;
      }
    }
  }
}

// ---------------------------------------------------------------------------
// FUSED attention kernel (final config, session-best total 461.3us,
// reproduced twice): R2 schedule with pow-2 swizzled LDS. Basin mapped
// from eight directions: swizzle(null) setprio(null) raw-barrier(regress)
// dbuf(spill) pairing(spill) 3-block(spill) 1-block(worse)
// small-block/fat-tile(worse) final-fusion(HBM-inefficient).
// Needs 128 regs/wave x 16 waves = full register file at 2 blocks/CU.
// ---------------------------------------------------------------------------
__global__ __launch_bounds__(512, 4) void attn_fused_kernel(
    const bf16* __restrict__ qkvT, const float* __restrict__ pos,
    const int* __restrict__ idx, const float* __restrict__ pw1,
    const float* __restrict__ pe_scale, const float* __restrict__ pe_shift,
    const bf16* __restrict__ pw2b, const float* __restrict__ pb2,
    const bf16* __restrict__ aw1b, const bf16* __restrict__ aw2b,
    const float* __restrict__ at_scale, const float* __restrict__ at_shift,
    const float* __restrict__ ab2, bf16* __restrict__ aggT)
{
  __shared__ __align__(16) bf16 u_lds[64 * 256];  // 32 KB, swizzled
  __shared__ __align__(16) bf16 tbuf[64 * 128];   // 16 KB: t / hid overlay
  __shared__ float rel_lds[64][4];
  __shared__ int   idx_lds[64];
  bf16* t_lds   = tbuf;                 // row stride 128, swizzled
  bf16* hid_lds = tbuf;                 // row stride 64, swizzled (8 KB)

  const int tid = threadIdx.x;
  const int lane = tid & 63, wave = tid >> 6;     // wave in [0,8)
  const int row16 = lane & 15, grp = lane >> 4;
  const int r7 = row16 & 7;
  const long c0 = (long)blockIdx.x * 64;
  const int bn0 = blockIdx.x * 4;
  const int b = bn0 >> 11;
  const float* pB = pos + (long)b * 3 * NPTS;
  const int os = wave * 32;             // this wave's 32-wide output slab

  // ---- stage idx + pos_rel + k rows (swizzled u write) ----
  if (tid < 64) {
    int nb = idx[c0 + tid];
    idx_lds[tid] = nb;
    int n = (bn0 + (tid >> 4)) & (NPTS - 1);
    rel_lds[tid][0] = pB[n] - pB[nb];
    rel_lds[tid][1] = pB[NPTS + n] - pB[NPTS + nb];
    rel_lds[tid][2] = pB[2 * NPTS + n] - pB[2 * NPTS + nb];
  }
#pragma unroll
  for (int it = 0; it < 4; ++it) {
    int id = it * 512 + tid;
    int col = id >> 5, ch16 = id & 31;
    int nb = idx[c0 + col];
    *(bf16x8*)&u_lds[col * 256 + ((ch16 ^ (col & 7)) << 3)] =
        *(const bf16x8*)(qkvT + ((long)b * NPTS + nb) * 768 + 256 + ch16 * 8);
  }
  __syncthreads();

  // ---- hid = relu(bn(pw1 . rel)) -> one swizzled b128 store/thread ----
  {
    int c = tid & 63, jq = tid >> 6;   // jq in [0,8)
    float rx = rel_lds[c][0], ry = rel_lds[c][1], rz = rel_lds[c][2];
    bf16x8 pk8;
#pragma unroll
    for (int jj = 0; jj < 8; ++jj) {
      int j = jq * 8 + jj;
      float v = pw1[j * 3] * rx + pw1[j * 3 + 1] * ry + pw1[j * 3 + 2] * rz;
      v = pe_scale[j] * v + pe_shift[j];
      pk8[jj] = (bf16)fmaxf(v, 0.f);
    }
    *(bf16x8*)&hid_lds[c * 64 + ((jq ^ (c & 7)) << 3)] = pk8;
  }
  __syncthreads();

  // ---- pe GEMM: accpe[ct][ot] holds pe[c=ct*16+grp*4+r][o=os+ot*16+row16] ----
  f32x4 accpe[4][2] = {};
#pragma unroll
  for (int ks = 0; ks < 2; ++ks) {
    bf16x8 ah[4];
#pragma unroll
    for (int ct = 0; ct < 4; ++ct)
      ah[ct] = *(const bf16x8*)&hid_lds[(ct * 16 + row16) * 64 + (((ks * 4 + grp) ^ r7) << 3)];
#pragma unroll
    for (int ot = 0; ot < 2; ++ot) {
      bf16x8 bw = *(const bf16x8*)(pw2b + (long)(os + ot * 16 + row16) * PH + ks * 32 + grp * 8);
#pragma unroll
      for (int ct = 0; ct < 4; ++ct)
        accpe[ct][ot] = __builtin_amdgcn_mfma_f32_16x16x32_bf16(ah[ct], bw, accpe[ct][ot], 0, 0, 0);
    }
  }

  // ---- u = q - k + pe (RMW on this wave's o-slab); keep pe as bf16 ----
  bf16x4 pe_bf[4][2];
#pragma unroll
  for (int ot = 0; ot < 2; ++ot) {
    int o = os + ot * 16 + row16;
    float pb2v = pb2[o];
#pragma unroll
    for (int ct = 0; ct < 4; ++ct) {
      float qv = (float)qkvT[(long)(bn0 + ct) * 768 + o];
#pragma unroll
      for (int r = 0; r < 4; ++r) {
        int c = ct * 16 + grp * 4 + r;
        int ua = c * 256 + (((o >> 3) ^ (c & 7)) << 3) + (o & 7);
        float pev = accpe[ct][ot][r] + pb2v;
        float kv = (float)u_lds[ua];
        u_lds[ua] = (bf16)(qv - kv + pev);
        pe_bf[ct][ot][r] = (bf16)pev;
      }
    }
  }
  __syncthreads();

  // ---- MLP: attn = ab2 + aw2 . relu(bn(aw1 . u)), HID chunked at 128 ----
  const int hs16 = wave * 16;
  f32x4 acc2[4][2] = {};
  for (int jc = 0; jc < 8; ++jc) {
    const int hg = jc * 128 + hs16;
    // GEMM1 (A=aw1 rows=j, B=u cols=c): D row=j, col=c
    f32x4 acc1[4] = {};
#pragma unroll
    for (int ks = 0; ks < 8; ++ks) {
      bf16x8 bu[4];
      const int ublk = ((ks * 4 + grp) ^ r7) << 3;
#pragma unroll
      for (int ct = 0; ct < 4; ++ct)
        bu[ct] = *(const bf16x8*)&u_lds[(ct * 16 + row16) * 256 + ublk];
      bf16x8 aw = *(const bf16x8*)(aw1b + (long)(hg + row16) * DIM + ks * 32 + grp * 8);
#pragma unroll
      for (int ct = 0; ct < 4; ++ct)
        acc1[ct] = __builtin_amdgcn_mfma_f32_16x16x32_bf16(aw, bu[ct], acc1[ct], 0, 0, 0);
    }
    // epilogue: lane holds t[c=ct*16+row16][j=hg+grp*4+r] -> swizzled b64
    {
      f32x4 sc4 = *(const f32x4*)&at_scale[hg + grp * 4];
      f32x4 sh4 = *(const f32x4*)&at_shift[hg + grp * 4];
#pragma unroll
      for (int ct = 0; ct < 4; ++ct) {
        bf16x4 pk;
#pragma unroll
        for (int r = 0; r < 4; ++r) {
          float v = sc4[r] * acc1[ct][r] + sh4[r];
          pk[r] = (bf16)fmaxf(v, 0.f);
        }
        int trow = ct * 16 + row16;
        int tblk = (wave * 2 + (grp >> 1)) ^ (trow & 7);
        *(bf16x4*)&t_lds[trow * 128 + (tblk << 3) + ((grp & 1) << 2)] = pk;
      }
    }
    __syncthreads();
    // GEMM2: acc2[c][o] += t[c][j] * aw2[o][j]
#pragma unroll
    for (int ks2 = 0; ks2 < 4; ++ks2) {
      bf16x8 a2[4], b2;
#pragma unroll
      for (int ct = 0; ct < 4; ++ct)
        a2[ct] = *(const bf16x8*)&t_lds[(ct * 16 + row16) * 128 + (((ks2 * 4 + grp) ^ r7) << 3)];
#pragma unroll
      for (int ot = 0; ot < 2; ++ot) {
        b2 = *(const bf16x8*)(aw2b + (long)(os + ot * 16 + row16) * HIDN + jc * 128 + ks2 * 32 + grp * 8);
#pragma unroll
        for (int ct = 0; ct < 4; ++ct)
          acc2[ct][ot] = __builtin_amdgcn_mfma_f32_16x16x32_bf16(a2[ct], b2, acc2[ct][ot], 0, 0, 0);
      }
    }
    __syncthreads();
  }

  // ---- softmax over K (k = grp*4+r across grp-lanes) + aggregation ----
#pragma unroll
  for (int ct = 0; ct < 4; ++ct) {
#pragma unroll
    for (int ot = 0; ot < 2; ++ot) {
      int o = os + ot * 16 + row16;
      float ab = ab2[o];
      float l[4];
      float m = -1e30f;
#pragma unroll
      for (int r = 0; r < 4; ++r) {
        l[r] = acc2[ct][ot][r] + ab;
        m = fmaxf(m, l[r]);
      }
      m = fmaxf(m, __shfl_xor(m, 16));
      m = fmaxf(m, __shfl_xor(m, 32));
      float s = 0.f;
#pragma unroll
      for (int r = 0; r < 4; ++r) { l[r] = __expf(l[r] - m); s += l[r]; }
      s += __shfl_xor(s, 16);
      s += __shfl_xor(s, 32);
      float inv = 1.f / s;
      float agg = 0.f;
#pragma unroll
      for (int r = 0; r < 4; ++r) {
        int c = ct * 16 + grp * 4 + r;
        int nb = idx_lds[c];
        float vv = (float)qkvT[((long)b * NPTS + nb) * 768 + 512 + o];
        agg += l[r] * (vv + (float)pe_bf[ct][ot][r]);
      }
      agg *= inv;
      agg += __shfl_xor(agg, 16);
      agg += __shfl_xor(agg, 32);
      if (grp == 0) aggT[(long)(bn0 + ct) * DIM + o] = (bf16)agg;
    }
  }
}

// ---------------------------------------------------------------------------
// final: out[b][o][n] = lw . agg + lb + identity  (fp32, channel-major out)
// ---------------------------------------------------------------------------
__global__ __launch_bounds__(256) void final_kernel(
    const bf16* __restrict__ aggT, const bf16* __restrict__ lwb,
    const float* __restrict__ lb, const float* __restrict__ x,
    float* __restrict__ out)
{
  const int tid = threadIdx.x;
  const int lane = tid & 63, wave = tid >> 6;
  const int row16 = lane & 15, grp = lane >> 4;
  const long i0 = (long)blockIdx.x * 64 + (wave & 1) * 32;
  const int o0 = blockIdx.y * 64 + (wave >> 1) * 32;
  f32x4 acc[2][2] = {};
  const bf16* a0p = aggT + (i0 + row16) * DIM + grp * 8;
  const bf16* a1p = a0p + 16 * DIM;
  const bf16* b0p = lwb + (long)(o0 + row16) * DIM + grp * 8;
  const bf16* b1p = b0p + 16 * DIM;
#pragma unroll
  for (int ks = 0; ks < 8; ++ks) {
    bf16x8 a0 = *(const bf16x8*)(a0p + ks * 32);
    bf16x8 a1 = *(const bf16x8*)(a1p + ks * 32);
    bf16x8 b0 = *(const bf16x8*)(b0p + ks * 32);
    bf16x8 b1 = *(const bf16x8*)(b1p + ks * 32);
    acc[0][0] = __builtin_amdgcn_mfma_f32_16x16x32_bf16(a0, b0, acc[0][0], 0, 0, 0);
    acc[0][1] = __builtin_amdgcn_mfma_f32_16x16x32_bf16(a0, b1, acc[0][1], 0, 0, 0);
    acc[1][0] = __builtin_amdgcn_mfma_f32_16x16x32_bf16(a1, b0, acc[1][0], 0, 0, 0);
    acc[1][1] = __builtin_amdgcn_mfma_f32_16x16x32_bf16(a1, b1, acc[1][1], 0, 0, 0);
  }
#pragma unroll
  for (int ot = 0; ot < 2; ++ot) {
    int o = o0 + ot * 16 + row16;
    float bv = lb[o];
#pragma unroll
    for (int it = 0; it < 2; ++it) {
#pragma unroll
      for (int r = 0; r < 4; ++r) {
        long i = i0 + it * 16 + grp * 4 + r;
        int bb = (int)(i >> 11);
        int n = (int)(i & (NPTS - 1));
        long off = ((long)bb * CIN + o) * NPTS + n;
        out[off] = acc[it][ot][r] + bv + x[off];
      }
    }
  }
}

// ---------------------------------------------------------------------------
extern "C" void kernel_launch(void* const* d_in, const int* in_sizes, int n_in,
                              void* d_out, int out_size, void* d_ws, size_t ws_size,
                              hipStream_t stream)
{
  const float* x     = (const float*)d_in[0];
  const float* pos   = (const float*)d_in[1];
  const float* ls_w  = (const float*)d_in[2];
  const float* ls_b  = (const float*)d_in[3];
  const float* kw    = (const float*)d_in[4];
  const float* kb    = (const float*)d_in[5];
  const float* qw    = (const float*)d_in[6];
  const float* qb    = (const float*)d_in[7];
  const float* vw    = (const float*)d_in[8];
  const float* vb    = (const float*)d_in[9];
  const float* pw1   = (const float*)d_in[10];
  const float* pb1   = (const float*)d_in[11];
  const float* pg    = (const float*)d_in[12];
  const float* pbeta = (const float*)d_in[13];
  const float* pmean = (const float*)d_in[14];
  const float* pvar  = (const float*)d_in[15];
  const float* pw2   = (const float*)d_in[16];
  const float* pb2   = (const float*)d_in[17];
  const float* aw1   = (const float*)d_in[18];
  const float* ab1   = (const float*)d_in[19];
  const float* ag    = (const float*)d_in[20];
  const float* abeta = (const float*)d_in[21];
  const float* amean = (const float*)d_in[22];
  const float* avar  = (const float*)d_in[23];
  const float* aw2   = (const float*)d_in[24];
  const float* ab2   = (const float*)d_in[25];
  const float* lw    = (const float*)d_in[26];
  const float* lb    = (const float*)d_in[27];

  char* ws = (char*)d_ws;
  size_t off = 0;
  auto alloc = [&](size_t bytes) -> void* {
    void* p = ws + off;
    off = (off + bytes + 255) & ~(size_t)255;
    return p;
  };

  bf16* pw2b  = (bf16*)alloc(16384 * 2);
  bf16* aw1b  = (bf16*)alloc(262144 * 2);
  bf16* aw2b  = (bf16*)alloc(262144 * 2);
  bf16* lwb   = (bf16*)alloc(32768 * 2);
  float* pe_scale = (float*)alloc(64 * 4);
  float* pe_shift = (float*)alloc(64 * 4);
  float* at_scale = (float*)alloc(1024 * 4);
  float* at_shift = (float*)alloc(1024 * 4);
  bf16* wfold = (bf16*)alloc(98304 * 2);    // 768 x 128
  float* bfold = (float*)alloc(768 * 4);
  int*  idx  = (int*)alloc((size_t)CC * 4);
  bf16* xT   = (bf16*)alloc((size_t)BN * CIN * 2);
  bf16* qkvT = (bf16*)alloc((size_t)BN * 768 * 2);
  bf16* aggT = (bf16*)alloc((size_t)BN * DIM * 2);

  // 1. combo: knn + prep + transpose + weight-fold (one launch)
  combo_kernel<<<dim3(FOLD_END), 256, 0, stream>>>(
      pos, idx, x, xT,
      ls_w, ls_b, qw, kw, vw, qb, kb, vb,
      pw2, aw1, aw2, lw,
      pb1, pg, pbeta, pmean, pvar, ab1, ag, abeta, amean, avar,
      pw2b, aw1b, aw2b, lwb,
      pe_scale, pe_shift, at_scale, at_shift,
      wfold, bfold);

  // 2. qkv = W' . x + b'  (ls projection folded; K=128)
  gemmT_kernel<128, true><<<dim3(BN / 64, 768 / 64), 256, 0, stream>>>(xT, wfold, bfold, qkvT, 768);

  // 3. fused attention (pe + u + MLP + softmax + agg) — 512 thr / 8 waves
  attn_fused_kernel<<<dim3(CC / 64), 512, 0, stream>>>(
      qkvT, pos, idx, pw1, pe_scale, pe_shift, pw2b, pb2,
      aw1b, aw2b, at_scale, at_shift, ab2, aggT);

  // 4. y = lw . agg + lb + identity
  final_kernel<<<dim3(BN / 64, CIN / 64), 256, 0, stream>>>(aggT, lwb, lb, x, (float*)d_out);
}